// Round 2
// baseline (999.563 us; speedup 1.0000x reference)
//
#include <hip/hip_runtime.h>

#define N_ROWS 131072
#define DIM 64
#define KCODES 1024
#define ROWS_PER_BLOCK 128
#define KSPLIT 2
#define KCHUNK (KCODES / KSPLIT)  // 512 codes per wave-group

typedef float v2f __attribute__((ext_vector_type(2)));

// Transpose embeddings [D][K] -> et [K][D] and compute h2[k] = 0.5*||e_k||^2.
__global__ __launch_bounds__(256) void vq_prep(const float* __restrict__ emb,
                                               float* __restrict__ et,
                                               float* __restrict__ h2) {
  int k = blockIdx.x * blockDim.x + threadIdx.x;  // 0..1023, coalesced over k
  float s = 0.f;
#pragma unroll
  for (int d = 0; d < DIM; ++d) {
    float v = emb[d * KCODES + k];
    et[k * DIM + d] = v;
    s = fmaf(v, v, s);
  }
  h2[k] = 0.5f * s;
}

// Block = 256 threads = 4 waves, handles 128 rows with a 2-way K split:
//   row  = blockIdx*128 + (tid & 127)
//   khalf = tid >> 7   (wave-uniform -> codebook loads stay scalar/SMEM)
// Codebook is read with wave-uniform addresses so the compiler emits
// s_load (scalar cache), keeping the LDS pipe idle; math is packed fp32.
__global__ __launch_bounds__(256) void vq_main(const float* __restrict__ x,
                                               const float* __restrict__ et,
                                               const float* __restrict__ h2,
                                               float* __restrict__ out) {
  __shared__ float s_val[256];
  __shared__ int   s_idx[256];

  const int tid = threadIdx.x;
  const int r   = tid & (ROWS_PER_BLOCK - 1);
  const int kh  = tid >> 7;  // 0 for waves 0-1, 1 for waves 2-3 (uniform per wave)
  const size_t row = (size_t)blockIdx.x * ROWS_PER_BLOCK + r;

  // Row into registers as 32 packed float2 (64 VGPRs).
  v2f f2[32];
  {
    const float4* xr = (const float4*)(x + row * DIM);
#pragma unroll
    for (int i = 0; i < 16; ++i) {
      float4 v = xr[i];
      f2[2 * i]     = (v2f){v.x, v.y};
      f2[2 * i + 1] = (v2f){v.z, v.w};
    }
  }

  float best = 3.4e38f;
  int bi = 0;
  const int k0 = kh * KCHUNK;
  for (int k = k0; k < k0 + KCHUNK; ++k) {
    const v2f* e2 = (const v2f*)(et + (size_t)k * DIM);  // uniform addr -> s_load
    v2f acc = {0.f, 0.f};
#pragma unroll
    for (int i = 0; i < 32; ++i)
      acc = __builtin_elementwise_fma(f2[i], e2[i], acc);  // v_pk_fma_f32
    float val = h2[k] - (acc.x + acc.y);  // 0.5||e||^2 - f.e, monotone in distance
    if (val < best) { best = val; bi = k; }  // strict <: first-min per half
  }

  s_val[tid] = best;
  s_idx[tid] = bi;
  __syncthreads();

  if (tid < ROWS_PER_BLOCK) {
    float v0 = s_val[tid];
    float v1 = s_val[tid + ROWS_PER_BLOCK];
    int   i0 = s_idx[tid];
    int   i1 = s_idx[tid + ROWS_PER_BLOCK];
    // low half has smaller indices: only take high half on strictly smaller val
    int widx = (v1 < v0) ? i1 : i0;
    const float4* q = (const float4*)(et + (size_t)widx * DIM);
    float4* o = (float4*)(out + ((size_t)blockIdx.x * ROWS_PER_BLOCK + tid) * DIM);
#pragma unroll
    for (int i = 0; i < 16; ++i) o[i] = q[i];
  }
}

extern "C" void kernel_launch(void* const* d_in, const int* in_sizes, int n_in,
                              void* d_out, int out_size, void* d_ws, size_t ws_size,
                              hipStream_t stream) {
  const float* x = (const float*)d_in[0];
  const float* emb = (const float*)d_in[1];
  float* out = (float*)d_out;

  float* et = (float*)d_ws;        // 1024*64 floats = 256 KiB
  float* h2 = et + KCODES * DIM;   // 1024 floats

  vq_prep<<<KCODES / 256, 256, 0, stream>>>(emb, et, h2);
  vq_main<<<N_ROWS / ROWS_PER_BLOCK, 256, 0, stream>>>(x, et, h2, out);
}

// Round 3
// 304.517 us; speedup vs baseline: 3.2825x; 3.2825x over previous
//
#include <hip/hip_runtime.h>

#define N_ROWS 131072
#define DIM 64
#define KCODES 1024
#define RPB 128       // rows per block
#define XSTRIDE 132   // padded LDS stride for xT in floats: 16B-aligned, banks decorrelated

// Transpose embeddings [D][K] -> et [K][D] and compute h2[k] = 0.5*||e_k||^2.
__global__ __launch_bounds__(256) void vq_prep(const float* __restrict__ emb,
                                               float* __restrict__ et,
                                               float* __restrict__ h2) {
  int k = blockIdx.x * blockDim.x + threadIdx.x;
  float s = 0.f;
#pragma unroll
  for (int d = 0; d < DIM; ++d) {
    float v = emb[d * KCODES + k];
    et[k * DIM + d] = v;
    s = fmaf(v, v, s);
  }
  h2[k] = 0.5f * s;
}

// GEMM-style register tiling: wave = 64 rows x 64 codes, lane = 8 rows x 8 codes.
// 64 FMA per 4 ds_read_b128 (vs 4 FMA/read in the naive broadcast loop).
__global__ __launch_bounds__(256, 2) void vq_main(const float* __restrict__ x,
                                                  const float* __restrict__ emb,
                                                  const float* __restrict__ et,
                                                  const float* __restrict__ h2,
                                                  float* __restrict__ out) {
  __shared__ float xT[DIM * XSTRIDE];   // [d][row], 33.8 KB
  __shared__ float eT[2][DIM * 64];     // [half][d][code], 32 KB
  __shared__ float eb_v[2][RPB];
  __shared__ int   eb_i[2][RPB];

  const int tid = threadIdx.x;
  const int w   = tid >> 6;   // wave 0..3
  const int l   = tid & 63;
  const int ri  = l & 7;      // row chunk within wave tile
  const int ci  = l >> 3;     // code chunk within wave tile
  const int s   = w & 1;      // row strip (64 rows)
  const int h   = w >> 1;     // code half (512 codes)
  const size_t rowbase = (size_t)blockIdx.x * RPB;

  // ---- stage x transposed: x[rowbase+row][d] -> xT[d][row] ----
  {
    const float4* xs = (const float4*)(x + rowbase * DIM);
    for (int i = tid; i < RPB * (DIM / 4); i += 256) {  // 2048 float4, coalesced
      float4 v = xs[i];
      int row = i >> 4, d = (i & 15) * 4;
      xT[(d + 0) * XSTRIDE + row] = v.x;
      xT[(d + 1) * XSTRIDE + row] = v.y;
      xT[(d + 2) * XSTRIDE + row] = v.z;
      xT[(d + 3) * XSTRIDE + row] = v.w;
    }
  }

  float best_v[8];
  int   best_i[8];
#pragma unroll
  for (int a = 0; a < 8; ++a) { best_v[a] = 3.4e38f; best_i[a] = 0; }

  for (int it = 0; it < 8; ++it) {
    __syncthreads();  // previous tile consumed (also covers xT staging on it=0)
    // stage e-tiles: eT[hh][d][c] = emb[d][hh*512 + it*64 + c], 2048 float4 coalesced
    for (int i = tid; i < 2 * DIM * 16; i += 256) {
      int hh = i >> 10;
      int r2 = i & 1023;
      int d = r2 >> 4, c4 = (r2 & 15) * 4;
      float4 v = *(const float4*)(emb + d * KCODES + hh * 512 + it * 64 + c4);
      *(float4*)(&eT[hh][d * 64 + c4]) = v;
    }
    __syncthreads();

    float acc[8][8];
#pragma unroll
    for (int a = 0; a < 8; ++a)
#pragma unroll
      for (int b = 0; b < 8; ++b) acc[a][b] = 0.f;

    const float* xb  = &xT[s * 64 + ri * 8];
    const float* ebp = &eT[h][ci * 8];
#pragma unroll 4
    for (int d = 0; d < DIM; ++d) {
      float4 r0 = *(const float4*)(xb + d * XSTRIDE);
      float4 r1 = *(const float4*)(xb + d * XSTRIDE + 4);
      float4 c0 = *(const float4*)(ebp + d * 64);
      float4 c1 = *(const float4*)(ebp + d * 64 + 4);
      float rr[8] = {r0.x, r0.y, r0.z, r0.w, r1.x, r1.y, r1.z, r1.w};
      float cc[8] = {c0.x, c0.y, c0.z, c0.w, c1.x, c1.y, c1.z, c1.w};
#pragma unroll
      for (int a = 0; a < 8; ++a)
#pragma unroll
        for (int b = 0; b < 8; ++b) acc[a][b] = fmaf(rr[a], cc[b], acc[a][b]);
    }

    // fold in 0.5*||e||^2 and merge into running per-row best
    const int kb = h * 512 + it * 64 + ci * 8;
    float4 ha = *(const float4*)(h2 + kb);
    float4 hb = *(const float4*)(h2 + kb + 4);
    float hh2[8] = {ha.x, ha.y, ha.z, ha.w, hb.x, hb.y, hb.z, hb.w};
#pragma unroll
    for (int a = 0; a < 8; ++a) {
#pragma unroll
      for (int b = 0; b < 8; ++b) {
        float val = hh2[b] - acc[a][b];  // 0.5||e||^2 - f.e, monotone in distance
        int idx = kb + b;
        if (val < best_v[a] || (val == best_v[a] && idx < best_i[a])) {
          best_v[a] = val; best_i[a] = idx;
        }
      }
    }
  }

  // reduce across the 8 ci-lanes (lane bits 3..5), lexicographic (val, idx)
#pragma unroll
  for (int m = 8; m <= 32; m <<= 1) {
#pragma unroll
    for (int a = 0; a < 8; ++a) {
      float ov = __shfl_xor(best_v[a], m, 64);
      int   oi = __shfl_xor(best_i[a], m, 64);
      if (ov < best_v[a] || (ov == best_v[a] && oi < best_i[a])) {
        best_v[a] = ov; best_i[a] = oi;
      }
    }
  }
  if (ci == 0) {
#pragma unroll
    for (int a = 0; a < 8; ++a) {
      int rl = s * 64 + ri * 8 + a;
      eb_v[h][rl] = best_v[a];
      eb_i[h][rl] = best_i[a];
    }
  }
  __syncthreads();

  // merge code halves, gather winning codebook row, coalesced store
  if (tid < RPB) {
    float v0 = eb_v[0][tid], v1 = eb_v[1][tid];
    int   i0 = eb_i[0][tid], i1 = eb_i[1][tid];
    int widx = (v1 < v0) ? i1 : i0;  // tie -> half 0 (smaller index), matches argmin-first
    const float4* q = (const float4*)(et + (size_t)widx * DIM);
    float4* o = (float4*)(out + (rowbase + tid) * DIM);
#pragma unroll
    for (int i = 0; i < 16; ++i) o[i] = q[i];
  }
}

extern "C" void kernel_launch(void* const* d_in, const int* in_sizes, int n_in,
                              void* d_out, int out_size, void* d_ws, size_t ws_size,
                              hipStream_t stream) {
  const float* x = (const float*)d_in[0];
  const float* emb = (const float*)d_in[1];
  float* out = (float*)d_out;

  float* et = (float*)d_ws;        // 1024*64 floats = 256 KiB
  float* h2 = et + KCODES * DIM;   // 1024 floats

  vq_prep<<<KCODES / 256, 256, 0, stream>>>(emb, et, h2);
  vq_main<<<N_ROWS / RPB, 256, 0, stream>>>(x, emb, et, h2, out);
}

// Round 4
// 231.821 us; speedup vs baseline: 4.3118x; 1.3136x over previous
//
#include <hip/hip_runtime.h>
#include <stdint.h>

typedef unsigned short ushortT;

#define NROWS 131072
#define DIM 64
#define KCODES 1024
#define NSEG 6
#define KTOT (NSEG * DIM)   // 384
#define NKC (KTOT / 32)     // 12 K-chunks of 32
#define MT 64               // rows per block
#define NTC 256             // codes per code-iter (4 waves x 64)
#define CI (KCODES / NTC)   // 4 code iters

typedef float f32x4 __attribute__((ext_vector_type(4)));
typedef short bf16x8 __attribute__((ext_vector_type(8)));

__device__ __forceinline__ ushortT f2bf(float f) {
  union { float f; uint32_t u; } v; v.f = f;
  return (ushortT)((v.u + 0x7FFFu + ((v.u >> 16) & 1u)) >> 16);  // RNE
}
__device__ __forceinline__ float bf2f(ushortT b) {
  union { float f; uint32_t u; } v; v.u = ((uint32_t)b) << 16;
  return v.f;
}

__device__ __forceinline__ void gload_lds16(const void* g, void* l) {
  __builtin_amdgcn_global_load_lds(
      (const __attribute__((address_space(1))) uint32_t*)g,
      (__attribute__((address_space(3))) uint32_t*)l, 16, 0, 0);
}

// Expand codebook: 3-level bf16 split, frag-major layout Bg[(kc*4+q)*1024+code][8],
// segment planes along K: sB = {e0,e1,e2,e0,e1,e0}. Also h2[k]=0.5*||e_k||^2 (fp32).
__global__ __launch_bounds__(256) void vq_prep(const float* __restrict__ emb,
                                               ushortT* __restrict__ Bg,
                                               float* __restrict__ h2) {
  const int code = blockIdx.x * 256 + threadIdx.x;
  float e[DIM];
  float s = 0.f;
#pragma unroll
  for (int d = 0; d < DIM; ++d) {
    e[d] = emb[d * KCODES + code];
    s = fmaf(e[d], e[d], s);
  }
  h2[code] = 0.5f * s;
#pragma unroll
  for (int d = 0; d < DIM; ++d) {
    ushortT p0 = f2bf(e[d]); float r1 = e[d] - bf2f(p0);   // exact (Sterbenz)
    ushortT p1 = f2bf(r1);   float r2 = r1 - bf2f(p1);     // exact
    ushortT p2 = f2bf(r2);
    const ushortT pv[3] = {p0, p1, p2};
    const int sB[6] = {0, 1, 2, 0, 1, 0};
#pragma unroll
    for (int seg = 0; seg < 6; ++seg) {
      int k = seg * DIM + d;
      int kc = k >> 5, q = (k >> 3) & 3, j = k & 7;
      Bg[((size_t)((kc * 4 + q) * KCODES + code)) * 8 + j] = pv[sB[seg]];
    }
  }
}

// Block: 64 rows x 1024 codes. A (rows, K=384 bf16) staged once frag-major in LDS;
// B streamed in 16KB chunks via global_load_lds. 16x16x32 bf16 MFMA, 4x4 acc/wave.
__global__ __launch_bounds__(256, 2) void vq_main(const float* __restrict__ x,
                                                  const ushortT* __restrict__ Bg,
                                                  const float* __restrict__ h2,
                                                  const float* __restrict__ emb,
                                                  float* __restrict__ out) {
  __shared__ ushortT A_lds[NKC * 4 * MT * 8];  // 48 KB  [kc][quad][row][8]
  __shared__ ushortT B_lds[4 * NTC * 8];       // 16 KB  [quad][code][8]
  __shared__ float bvs[4][MT];
  __shared__ int bis[4][MT];
  __shared__ int widx_s[MT];

  const int tid = threadIdx.x;
  const int wave = tid >> 6, lane = tid & 63, quad = lane >> 4, lq = lane & 15;
  const size_t rowbase = (size_t)blockIdx.x * MT;

  // ---- stage A: x rows -> 3 bf16 planes, frag-major. thread: row=tid>>2, 16 d's ----
  {
    const int row = tid >> 2, dg = (tid & 3) << 4;
    const float4* xr = (const float4*)(x + (rowbase + row) * DIM + dg);
    float v[16];
#pragma unroll
    for (int i = 0; i < 4; ++i) {
      float4 t = xr[i];
      v[4 * i] = t.x; v[4 * i + 1] = t.y; v[4 * i + 2] = t.z; v[4 * i + 3] = t.w;
    }
    ushortT pl[3][16];
#pragma unroll
    for (int i = 0; i < 16; ++i) {
      ushortT a0 = f2bf(v[i]); float r1 = v[i] - bf2f(a0);
      ushortT a1 = f2bf(r1);   float r2 = r1 - bf2f(a1);
      pl[0][i] = a0; pl[1][i] = a1; pl[2][i] = f2bf(r2);
    }
    const int sA[6] = {0, 0, 0, 1, 1, 2};  // x-plane per segment
    const int q0 = (dg & 31) >> 3;         // 0 or 2
#pragma unroll
    for (int seg = 0; seg < 6; ++seg) {
      int kc = seg * 2 + (dg >> 5);
      *(uint4*)&A_lds[(((kc * 4 + q0) * MT) + row) * 8]     = *(uint4*)&pl[sA[seg]][0];
      *(uint4*)&A_lds[(((kc * 4 + q0 + 1) * MT) + row) * 8] = *(uint4*)&pl[sA[seg]][8];
    }
  }

  float bestv[4][4];
  int besti[4][4];
#pragma unroll
  for (int i = 0; i < 4; ++i)
#pragma unroll
    for (int r = 0; r < 4; ++r) { bestv[i][r] = 3.4e38f; besti[i][r] = 0; }

  for (int ci = 0; ci < CI; ++ci) {
    const int codeBase = ci * NTC;
    f32x4 acc[4][4];
#pragma unroll
    for (int i = 0; i < 4; ++i)
#pragma unroll
      for (int j = 0; j < 4; ++j) acc[i][j] = (f32x4){0.f, 0.f, 0.f, 0.f};

    for (int kc = 0; kc < NKC; ++kc) {
      __syncthreads();  // B_lds consumed (first iter: covers A staging too)
#pragma unroll
      for (int q = 0; q < 4; ++q) {
        const ushortT* g = Bg + ((size_t)((kc * 4 + q) * KCODES + codeBase + tid)) * 8;
        gload_lds16(g, &B_lds[(q * NTC + tid) * 8]);
      }
      __syncthreads();  // drains vmcnt (global_load_lds) per barrier semantics

      bf16x8 a[4], b[4];
#pragma unroll
      for (int i = 0; i < 4; ++i)
        a[i] = *(const bf16x8*)&A_lds[(((kc * 4 + quad) * MT) + i * 16 + lq) * 8];
#pragma unroll
      for (int j = 0; j < 4; ++j)
        b[j] = *(const bf16x8*)&B_lds[(quad * NTC + wave * 64 + j * 16 + lq) * 8];
#pragma unroll
      for (int i = 0; i < 4; ++i)
#pragma unroll
        for (int j = 0; j < 4; ++j)
          acc[i][j] = __builtin_amdgcn_mfma_f32_16x16x32_bf16(a[i], b[j], acc[i][j], 0, 0, 0);
    }

    // epilogue: val = 0.5||e||^2 - f.e ; merge into per-row running best
    float h2v[4];
#pragma unroll
    for (int j = 0; j < 4; ++j) h2v[j] = h2[codeBase + wave * 64 + j * 16 + lq];
#pragma unroll
    for (int i = 0; i < 4; ++i)
#pragma unroll
      for (int j = 0; j < 4; ++j) {
        const int idx = codeBase + wave * 64 + j * 16 + lq;
#pragma unroll
        for (int r = 0; r < 4; ++r) {
          float val = h2v[j] - acc[i][j][r];
          if (val < bestv[i][r]) { bestv[i][r] = val; besti[i][r] = idx; }  // idx ascending in (ci,j): strict < keeps lowest
        }
      }
  }

  // reduce across the 16 lanes sharing a quad (lane bits 0-3), lexicographic (val, idx)
#pragma unroll
  for (int m = 1; m < 16; m <<= 1) {
#pragma unroll
    for (int i = 0; i < 4; ++i)
#pragma unroll
      for (int r = 0; r < 4; ++r) {
        float ov = __shfl_xor(bestv[i][r], m, 64);
        int oi = __shfl_xor(besti[i][r], m, 64);
        if (ov < bestv[i][r] || (ov == bestv[i][r] && oi < besti[i][r])) {
          bestv[i][r] = ov; besti[i][r] = oi;
        }
      }
  }
  if (lq == 0) {
#pragma unroll
    for (int i = 0; i < 4; ++i)
#pragma unroll
      for (int r = 0; r < 4; ++r) {
        int row = i * 16 + quad * 4 + r;
        bvs[wave][row] = bestv[i][r];
        bis[wave][row] = besti[i][r];
      }
  }
  __syncthreads();
  if (tid < MT) {
    float bv = bvs[0][tid]; int bi = bis[0][tid];
#pragma unroll
    for (int w = 1; w < 4; ++w) {
      float ov = bvs[w][tid]; int oi = bis[w][tid];
      if (ov < bv || (ov == bv && oi < bi)) { bv = ov; bi = oi; }
    }
    widx_s[tid] = bi;
  }
  __syncthreads();
  // cooperative gather: thread handles row=tid>>2, 16 d's; emb is L2-resident (256KB)
  {
    const int row = tid >> 2, dg = (tid & 3) << 4;
    const int wi = widx_s[row];
    float4* o = (float4*)(out + (rowbase + row) * DIM + dg);
#pragma unroll
    for (int i = 0; i < 4; ++i) {
      float4 t;
      t.x = emb[(dg + 4 * i + 0) * KCODES + wi];
      t.y = emb[(dg + 4 * i + 1) * KCODES + wi];
      t.z = emb[(dg + 4 * i + 2) * KCODES + wi];
      t.w = emb[(dg + 4 * i + 3) * KCODES + wi];
      o[i] = t;
    }
  }
}

extern "C" void kernel_launch(void* const* d_in, const int* in_sizes, int n_in,
                              void* d_out, int out_size, void* d_ws, size_t ws_size,
                              hipStream_t stream) {
  const float* x = (const float*)d_in[0];
  const float* emb = (const float*)d_in[1];
  float* out = (float*)d_out;

  ushortT* Bg = (ushortT*)d_ws;               // 12*4*1024*8 ushort = 768 KB
  float* h2 = (float*)(Bg + NKC * 4 * KCODES * 8);  // 4 KB

  vq_prep<<<KCODES / 256, 256, 0, stream>>>(emb, Bg, h2);
  vq_main<<<NROWS / MT, 256, 0, stream>>>(x, Bg, h2, emb, out);
}